// Round 3
// baseline (745.183 us; speedup 1.0000x reference)
//
#include <hip/hip_runtime.h>

#define T_DIM 2048
#define H_DIM 256
#define B_DIM 64
#define CHUNK 64
#define NCH (T_DIM / CHUNK)   /* 32 chunks per batch row */
#define NCB (B_DIM * NCH)     /* 2048 blocks */
#define EPS_F 1e-4f

// mu and inv-sd (= 1/max(sqrt(var),EPS)) from window sums.
__device__ __forceinline__ void win_stats(float s1, float s2, float inv_w, float inv_wm1,
                                          float& mu, float& isd) {
    mu = s1 * inv_w;
    float var = fmaxf((s2 - s1 * s1 * inv_w) * inv_wm1, 0.0f);
    // 1/max(sqrt(var),1e-4) == min(rsqrt(var), 1e4); rsqrt(0)=inf -> 1e4. Matches ref.
    isd = fminf(rsqrtf(var), 1e4f);
}

// Inner loop body shared by both passes; FIRST=true adds the t<w edge handling.
// PASS 0: accumulate ls1/ls2 (slice partials). PASS 1: y = fan*A+B, out = v+y.
template <int PASS, bool FIRST>
__device__ __forceinline__ void run_chunk(
    const float* __restrict__ xbh, int t0, float al0, float al1, float al2,
    float A, float Bc, float* __restrict__ outbh,
    float& ls1, float& ls2,
    float mu5i, float isd5i, float mu10i, float isd10i, float mu20i, float isd20i) {

    float s1_5 = 0.f, s2_5 = 0.f, s1_10 = 0.f, s2_10 = 0.f, s1_20 = 0.f, s2_20 = 0.f;
    float hist[32];

    if (FIRST) {
#pragma unroll
        for (int j = 0; j < 32; ++j) hist[j] = 0.0f;
    } else {
        // Warm-up: window sums covering [t0-20, t0); delay-line positions 12..31.
#pragma unroll
        for (int j = 1; j <= 20; ++j) {
            float v = xbh[(t0 - j) * H_DIM];
            hist[(32 - j) & 31] = v;
            s1_20 += v; s2_20 += v * v;
            if (j <= 10) { s1_10 += v; s2_10 += v * v; }
            if (j <= 5)  { s1_5  += v; s2_5  += v * v; }
        }
    }

    for (int i0 = 0; i0 < CHUNK; i0 += 32) {
#pragma unroll
        for (int k = 0; k < 32; ++k) {
            const int t = t0 + i0 + k;   // FIRST => t == i0+k (compile-time per k)
            const float v = xbh[t * H_DIM];
            hist[k] = v;
            s1_5  += v; s2_5  += v * v;
            s1_10 += v; s2_10 += v * v;
            s1_20 += v; s2_20 += v * v;
            if (!FIRST || i0 + k >= 5)  { float o = hist[(k - 5)  & 31]; s1_5  -= o; s2_5  -= o * o; }
            if (!FIRST || i0 + k >= 10) { float o = hist[(k - 10) & 31]; s1_10 -= o; s2_10 -= o * o; }
            if (!FIRST || i0 + k >= 20) { float o = hist[(k - 20) & 31]; s1_20 -= o; s2_20 -= o * o; }

            float mu, isd, fan = 0.0f;
            if (!FIRST || i0 + k >= 4)  win_stats(s1_5,  s2_5,  0.2f,  0.25f,      mu, isd);
            else { mu = mu5i;  isd = isd5i; }
            fan += (v - mu) * isd * al0;
            if (!FIRST || i0 + k >= 9)  win_stats(s1_10, s2_10, 0.1f,  1.f / 9.f,  mu, isd);
            else { mu = mu10i; isd = isd10i; }
            fan += (v - mu) * isd * al1;
            if (!FIRST || i0 + k >= 19) win_stats(s1_20, s2_20, 0.05f, 1.f / 19.f, mu, isd);
            else { mu = mu20i; isd = isd20i; }
            fan += (v - mu) * isd * al2;

            if (PASS == 0) {
                ls1 += fan; ls2 += fan * fan;
            } else {
                outbh[t * H_DIM] = v + fmaf(fan, A, Bc);
            }
        }
    }
}

// PASS 0: FAN -> per-block per-h sum/sumsq partials (slice membership applied in reduce).
// PASS 1: recompute FAN identically, y = fan*A+B (A,B hoisted per block), residual, out.
template <int PASS>
__global__ __launch_bounds__(256, 6)
void fan_kernel(const float* __restrict__ x, const float* __restrict__ alpha,
                const float* __restrict__ gamma, const float* __restrict__ beta,
                float* __restrict__ part, const float* __restrict__ acc,
                float* __restrict__ out) {
    const int blk = blockIdx.x;
    const int b = blk / NCH;
    const int c = blk % NCH;
    const int h = threadIdx.x;
    const int t0 = c * CHUNK;
    const float* xbh = x + (size_t)b * T_DIM * H_DIM + h;
    float* outbh = out + (size_t)b * T_DIM * H_DIM + h;

    // softmax over alpha[h][0..2]
    const float a0 = alpha[h * 3 + 0], a1 = alpha[h * 3 + 1], a2 = alpha[h * 3 + 2];
    const float mx = fmaxf(a0, fmaxf(a1, a2));
    const float e0 = __expf(a0 - mx), e1 = __expf(a1 - mx), e2 = __expf(a2 - mx);
    const float einv = 1.0f / (e0 + e1 + e2);
    const float al0 = e0 * einv, al1 = e1 * einv, al2 = e2 * einv;

    // PASS1: fold SAN into y = fan*A + B. Regions are chunk-aligned:
    // slice0=[0,1536) (c<24), slice1=[1024,2048) (c>=16), overlap c in [16,24).
    float A = 0.f, Bc = 0.f;
    if (PASS == 1) {
        const float N0 = 64.0f * 1536.0f, N1 = 64.0f * 1024.0f;
        float S10 = acc[0 * H_DIM + h], S20 = acc[1 * H_DIM + h];
        float S11 = acc[2 * H_DIM + h], S21 = acc[3 * H_DIM + h];
        float mu0 = S10 / N0;
        float v0 = fmaxf((S20 - S10 * S10 / N0) / (N0 - 1.0f), 0.0f);
        float isd0 = 1.0f / fmaxf(sqrtf(v0), EPS_F);
        float mu1 = S11 / N1;
        float v1 = fmaxf((S21 - S11 * S11 / N1) / (N1 - 1.0f), 0.0f);
        float isd1 = 1.0f / fmaxf(sqrtf(v1), EPS_F);
        float A0 = isd0 * gamma[0 * H_DIM + h], B0 = beta[0 * H_DIM + h] - mu0 * A0;
        float A1 = isd1 * gamma[1 * H_DIM + h], B1 = beta[1 * H_DIM + h] - mu1 * A1;
        const float r1 = 1.0f / 1.0001f, r2 = 1.0f / 2.0001f;
        if (c < 16)      { A = A0 * r1;        Bc = B0 * r1; }
        else if (c >= 24){ A = A1 * r1;        Bc = B1 * r1; }
        else             { A = (A0 + A1) * r2; Bc = (B0 + B1) * r2; }
    }

    float ls1 = 0.0f, ls2 = 0.0f;

    if (c == 0) {
        // Edge stats: windows [0,w) used for t < w-1 (reference edge-pad semantics).
        float mu5i, isd5i, mu10i, isd10i, mu20i, isd20i;
        float c1 = 0.f, c2 = 0.f;
#pragma unroll
        for (int j = 0; j < 20; ++j) {
            float v = xbh[j * H_DIM];
            c1 += v; c2 += v * v;
            if (j == 4)  win_stats(c1, c2, 0.2f,  0.25f,      mu5i,  isd5i);
            if (j == 9)  win_stats(c1, c2, 0.1f,  1.f / 9.f,  mu10i, isd10i);
            if (j == 19) win_stats(c1, c2, 0.05f, 1.f / 19.f, mu20i, isd20i);
        }
        run_chunk<PASS, true>(xbh, t0, al0, al1, al2, A, Bc, outbh, ls1, ls2,
                              mu5i, isd5i, mu10i, isd10i, mu20i, isd20i);
    } else {
        run_chunk<PASS, false>(xbh, t0, al0, al1, al2, A, Bc, outbh, ls1, ls2,
                               0.f, 0.f, 0.f, 0.f, 0.f, 0.f);
    }

    if (PASS == 0) {
        part[(0 * NCB + blk) * H_DIM + h] = ls1;
        part[(1 * NCB + blk) * H_DIM + h] = ls2;
    }
}

// 32 blocks: (slice k, 1/16th of blocks). Membership by chunk index:
// slice0: c<24, slice1: c>=16. Atomic-add into acc[4][256].
__global__ __launch_bounds__(256)
void reduce_kernel(const float* __restrict__ part, float* __restrict__ acc) {
    const int h = threadIdx.x;
    const int k = blockIdx.x >> 4;     // slice 0/1
    const int g = blockIdx.x & 15;
    float a1 = 0.f, a2 = 0.f;
    for (int i = 0; i < NCB / 16; ++i) {
        const int blk = g * (NCB / 16) + i;
        const int c = blk % NCH;
        const bool member = (k == 0) ? (c < 24) : (c >= 16);
        if (member) {
            a1 += part[(0 * NCB + blk) * H_DIM + h];
            a2 += part[(1 * NCB + blk) * H_DIM + h];
        }
    }
    atomicAdd(&acc[(2 * k)     * H_DIM + h], a1);
    atomicAdd(&acc[(2 * k + 1) * H_DIM + h], a2);
}

extern "C" void kernel_launch(void* const* d_in, const int* in_sizes, int n_in,
                              void* d_out, int out_size, void* d_ws, size_t ws_size,
                              hipStream_t stream) {
    const float* x     = (const float*)d_in[0];
    const float* alpha = (const float*)d_in[1];
    const float* gamma = (const float*)d_in[2];
    const float* beta  = (const float*)d_in[3];
    float* out  = (float*)d_out;
    float* part = (float*)d_ws;                       // 2*NCB*H_DIM floats = 4 MB
    float* acc  = part + 2 * NCB * H_DIM;             // 4*H_DIM floats = 4 KB

    hipMemsetAsync(acc, 0, 4 * H_DIM * sizeof(float), stream);
    fan_kernel<0><<<NCB, H_DIM, 0, stream>>>(x, alpha, gamma, beta, part, acc, out);
    reduce_kernel<<<32, H_DIM, 0, stream>>>(part, acc);
    fan_kernel<1><<<NCB, H_DIM, 0, stream>>>(x, alpha, gamma, beta, part, acc, out);
}

// Round 4
// 434.568 us; speedup vs baseline: 1.7148x; 1.7148x over previous
//
#include <hip/hip_runtime.h>

#define T_DIM 2048
#define H_DIM 256
#define B_DIM 64
#define CHUNK 64
#define NCH (T_DIM / CHUNK)   /* 32 chunks per batch row */
#define NCB (B_DIM * NCH)     /* 2048 blocks */
#define EPS_F 1e-4f

// mu and inv-sd (= 1/max(sqrt(var),EPS)) from window sums.
__device__ __forceinline__ void win_stats(float s1, float s2, float inv_w, float inv_wm1,
                                          float& mu, float& isd) {
    mu = s1 * inv_w;
    float var = fmaxf((s2 - s1 * s1 * inv_w) * inv_wm1, 0.0f);
    // 1/max(sqrt(var),1e-4) == min(rsqrt(var), 1e4); rsqrt(0)=inf -> 1e4. Matches ref.
    isd = fminf(rsqrtf(var), 1e4f);
}

// Inner loop body shared by both passes; FIRST=true adds the t<w edge handling.
// PASS 0: accumulate ls1/ls2 (slice partials). PASS 1: y = fan*A+B, out = v+y.
template <int PASS, bool FIRST>
__device__ __forceinline__ void run_chunk(
    const float* __restrict__ xbh, int t0, float al0, float al1, float al2,
    float A, float Bc, float* __restrict__ outbh,
    float& ls1, float& ls2,
    float mu5i, float isd5i, float mu10i, float isd10i, float mu20i, float isd20i) {

    float s1_5 = 0.f, s2_5 = 0.f, s1_10 = 0.f, s2_10 = 0.f, s1_20 = 0.f, s2_20 = 0.f;
    float hist[32];

    if (FIRST) {
#pragma unroll
        for (int j = 0; j < 32; ++j) hist[j] = 0.0f;
    } else {
        // Warm-up: window sums covering [t0-20, t0); delay-line positions 12..31.
#pragma unroll
        for (int j = 1; j <= 20; ++j) {
            float v = xbh[(t0 - j) * H_DIM];
            hist[(32 - j) & 31] = v;
            s1_20 += v; s2_20 += v * v;
            if (j <= 10) { s1_10 += v; s2_10 += v * v; }
            if (j <= 5)  { s1_5  += v; s2_5  += v * v; }
        }
    }

    for (int i0 = 0; i0 < CHUNK; i0 += 32) {
#pragma unroll
        for (int k = 0; k < 32; ++k) {
            const int t = t0 + i0 + k;   // FIRST => t == i0+k (compile-time per k)
            const float v = xbh[t * H_DIM];
            hist[k] = v;
            s1_5  += v; s2_5  += v * v;
            s1_10 += v; s2_10 += v * v;
            s1_20 += v; s2_20 += v * v;
            if (!FIRST || i0 + k >= 5)  { float o = hist[(k - 5)  & 31]; s1_5  -= o; s2_5  -= o * o; }
            if (!FIRST || i0 + k >= 10) { float o = hist[(k - 10) & 31]; s1_10 -= o; s2_10 -= o * o; }
            if (!FIRST || i0 + k >= 20) { float o = hist[(k - 20) & 31]; s1_20 -= o; s2_20 -= o * o; }

            float mu, isd, fan = 0.0f;
            if (!FIRST || i0 + k >= 4)  win_stats(s1_5,  s2_5,  0.2f,  0.25f,      mu, isd);
            else { mu = mu5i;  isd = isd5i; }
            fan += (v - mu) * isd * al0;
            if (!FIRST || i0 + k >= 9)  win_stats(s1_10, s2_10, 0.1f,  1.f / 9.f,  mu, isd);
            else { mu = mu10i; isd = isd10i; }
            fan += (v - mu) * isd * al1;
            if (!FIRST || i0 + k >= 19) win_stats(s1_20, s2_20, 0.05f, 1.f / 19.f, mu, isd);
            else { mu = mu20i; isd = isd20i; }
            fan += (v - mu) * isd * al2;

            if (PASS == 0) {
                ls1 += fan; ls2 += fan * fan;
            } else {
                outbh[t * H_DIM] = v + fmaf(fan, A, Bc);
            }
        }
    }
}

// PASS 0: FAN -> per-block per-h sum/sumsq partials (slice membership applied in reduce).
// PASS 1: recompute FAN identically, y = fan*A+B (A,B hoisted per block), residual, out.
// NOTE: needs ~80 VGPRs live (hist[32] + sums). Bounding below 4 waves/EU (128 VGPR
// cap) forces spill-to-scratch: R3 with (256,6) -> 40 VGPR, 858 MB scratch writes, 2x slower.
template <int PASS>
__global__ __launch_bounds__(256, 4)
void fan_kernel(const float* __restrict__ x, const float* __restrict__ alpha,
                const float* __restrict__ gamma, const float* __restrict__ beta,
                float* __restrict__ part, const float* __restrict__ acc,
                float* __restrict__ out) {
    const int blk = blockIdx.x;
    const int b = blk / NCH;
    const int c = blk % NCH;
    const int h = threadIdx.x;
    const int t0 = c * CHUNK;
    const float* xbh = x + (size_t)b * T_DIM * H_DIM + h;
    float* outbh = out + (size_t)b * T_DIM * H_DIM + h;

    // softmax over alpha[h][0..2]
    const float a0 = alpha[h * 3 + 0], a1 = alpha[h * 3 + 1], a2 = alpha[h * 3 + 2];
    const float mx = fmaxf(a0, fmaxf(a1, a2));
    const float e0 = __expf(a0 - mx), e1 = __expf(a1 - mx), e2 = __expf(a2 - mx);
    const float einv = 1.0f / (e0 + e1 + e2);
    const float al0 = e0 * einv, al1 = e1 * einv, al2 = e2 * einv;

    // PASS1: fold SAN into y = fan*A + B. Regions are chunk-aligned:
    // slice0=[0,1536) (c<24), slice1=[1024,2048) (c>=16), overlap c in [16,24).
    float A = 0.f, Bc = 0.f;
    if (PASS == 1) {
        const float N0 = 64.0f * 1536.0f, N1 = 64.0f * 1024.0f;
        float S10 = acc[0 * H_DIM + h], S20 = acc[1 * H_DIM + h];
        float S11 = acc[2 * H_DIM + h], S21 = acc[3 * H_DIM + h];
        float mu0 = S10 / N0;
        float v0 = fmaxf((S20 - S10 * S10 / N0) / (N0 - 1.0f), 0.0f);
        float isd0 = 1.0f / fmaxf(sqrtf(v0), EPS_F);
        float mu1 = S11 / N1;
        float v1 = fmaxf((S21 - S11 * S11 / N1) / (N1 - 1.0f), 0.0f);
        float isd1 = 1.0f / fmaxf(sqrtf(v1), EPS_F);
        float A0 = isd0 * gamma[0 * H_DIM + h], B0 = beta[0 * H_DIM + h] - mu0 * A0;
        float A1 = isd1 * gamma[1 * H_DIM + h], B1 = beta[1 * H_DIM + h] - mu1 * A1;
        const float r1 = 1.0f / 1.0001f, r2 = 1.0f / 2.0001f;
        if (c < 16)      { A = A0 * r1;        Bc = B0 * r1; }
        else if (c >= 24){ A = A1 * r1;        Bc = B1 * r1; }
        else             { A = (A0 + A1) * r2; Bc = (B0 + B1) * r2; }
    }

    float ls1 = 0.0f, ls2 = 0.0f;

    if (c == 0) {
        // Edge stats: windows [0,w) used for t < w-1 (reference edge-pad semantics).
        float mu5i, isd5i, mu10i, isd10i, mu20i, isd20i;
        float c1 = 0.f, c2 = 0.f;
#pragma unroll
        for (int j = 0; j < 20; ++j) {
            float v = xbh[j * H_DIM];
            c1 += v; c2 += v * v;
            if (j == 4)  win_stats(c1, c2, 0.2f,  0.25f,      mu5i,  isd5i);
            if (j == 9)  win_stats(c1, c2, 0.1f,  1.f / 9.f,  mu10i, isd10i);
            if (j == 19) win_stats(c1, c2, 0.05f, 1.f / 19.f, mu20i, isd20i);
        }
        run_chunk<PASS, true>(xbh, t0, al0, al1, al2, A, Bc, outbh, ls1, ls2,
                              mu5i, isd5i, mu10i, isd10i, mu20i, isd20i);
    } else {
        run_chunk<PASS, false>(xbh, t0, al0, al1, al2, A, Bc, outbh, ls1, ls2,
                               0.f, 0.f, 0.f, 0.f, 0.f, 0.f);
    }

    if (PASS == 0) {
        part[(0 * NCB + blk) * H_DIM + h] = ls1;
        part[(1 * NCB + blk) * H_DIM + h] = ls2;
    }
}

// 32 blocks: (slice k, 1/16th of blocks). Membership by chunk index:
// slice0: c<24, slice1: c>=16. Atomic-add into acc[4][256].
__global__ __launch_bounds__(256)
void reduce_kernel(const float* __restrict__ part, float* __restrict__ acc) {
    const int h = threadIdx.x;
    const int k = blockIdx.x >> 4;     // slice 0/1
    const int g = blockIdx.x & 15;
    float a1 = 0.f, a2 = 0.f;
    for (int i = 0; i < NCB / 16; ++i) {
        const int blk = g * (NCB / 16) + i;
        const int c = blk % NCH;
        const bool member = (k == 0) ? (c < 24) : (c >= 16);
        if (member) {
            a1 += part[(0 * NCB + blk) * H_DIM + h];
            a2 += part[(1 * NCB + blk) * H_DIM + h];
        }
    }
    atomicAdd(&acc[(2 * k)     * H_DIM + h], a1);
    atomicAdd(&acc[(2 * k + 1) * H_DIM + h], a2);
}

extern "C" void kernel_launch(void* const* d_in, const int* in_sizes, int n_in,
                              void* d_out, int out_size, void* d_ws, size_t ws_size,
                              hipStream_t stream) {
    const float* x     = (const float*)d_in[0];
    const float* alpha = (const float*)d_in[1];
    const float* gamma = (const float*)d_in[2];
    const float* beta  = (const float*)d_in[3];
    float* out  = (float*)d_out;
    float* part = (float*)d_ws;                       // 2*NCB*H_DIM floats = 4 MB
    float* acc  = part + 2 * NCB * H_DIM;             // 4*H_DIM floats = 4 KB

    hipMemsetAsync(acc, 0, 4 * H_DIM * sizeof(float), stream);
    fan_kernel<0><<<NCB, H_DIM, 0, stream>>>(x, alpha, gamma, beta, part, acc, out);
    reduce_kernel<<<32, H_DIM, 0, stream>>>(part, acc);
    fan_kernel<1><<<NCB, H_DIM, 0, stream>>>(x, alpha, gamma, beta, part, acc, out);
}

// Round 5
// 365.349 us; speedup vs baseline: 2.0396x; 1.1895x over previous
//
#include <hip/hip_runtime.h>

#define T_DIM 2048
#define H_DIM 256
#define B_DIM 64
#define CHUNK 64
#define NCH (T_DIM / CHUNK)   /* 32 chunks per batch row */
#define NCB (B_DIM * NCH)     /* 2048 blocks */
#define EPS_F 1e-4f

// mu and inv-sd (= 1/max(sqrt(var),EPS)) from window sums.
__device__ __forceinline__ void win_stats(float s1, float s2, float inv_w, float inv_wm1,
                                          float& mu, float& isd) {
    mu = s1 * inv_w;
    float var = fmaxf((s2 - s1 * s1 * inv_w) * inv_wm1, 0.0f);
    // 1/max(sqrt(var),1e-4) == min(rsqrt(var), 1e4); rsqrt(0)=inf -> 1e4. Matches ref.
    isd = fminf(rsqrtf(var), 1e4f);
}

// Inner loop body shared by both passes; FIRST=true adds the t<w edge handling.
// PASS 0: accumulate ls1/ls2 (slice partials). PASS 1: y = fan*A+B, out = v+y.
template <int PASS, bool FIRST>
__device__ __forceinline__ void run_chunk(
    const float* __restrict__ xbh, int t0, float al0, float al1, float al2,
    float A, float Bc, float* __restrict__ outbh,
    float& ls1, float& ls2,
    float mu5i, float isd5i, float mu10i, float isd10i, float mu20i, float isd20i) {

    float s1_5 = 0.f, s2_5 = 0.f, s1_10 = 0.f, s2_10 = 0.f, s1_20 = 0.f, s2_20 = 0.f;
    float hist[32];

    if (FIRST) {
#pragma unroll
        for (int j = 0; j < 32; ++j) hist[j] = 0.0f;
    } else {
        // Warm-up: window sums covering [t0-20, t0); delay-line positions 12..31.
#pragma unroll
        for (int j = 1; j <= 20; ++j) {
            float v = xbh[(t0 - j) * H_DIM];
            hist[(32 - j) & 31] = v;
            s1_20 += v; s2_20 += v * v;
            if (j <= 10) { s1_10 += v; s2_10 += v * v; }
            if (j <= 5)  { s1_5  += v; s2_5  += v * v; }
        }
    }

    for (int i0 = 0; i0 < CHUNK; i0 += 32) {
#pragma unroll
        for (int k = 0; k < 32; ++k) {
            const int t = t0 + i0 + k;   // FIRST => t == i0+k (compile-time per k)
            const float v = xbh[t * H_DIM];
            hist[k] = v;
            s1_5  += v; s2_5  += v * v;
            s1_10 += v; s2_10 += v * v;
            s1_20 += v; s2_20 += v * v;
            if (!FIRST || i0 + k >= 5)  { float o = hist[(k - 5)  & 31]; s1_5  -= o; s2_5  -= o * o; }
            if (!FIRST || i0 + k >= 10) { float o = hist[(k - 10) & 31]; s1_10 -= o; s2_10 -= o * o; }
            if (!FIRST || i0 + k >= 20) { float o = hist[(k - 20) & 31]; s1_20 -= o; s2_20 -= o * o; }

            float mu, isd, fan = 0.0f;
            if (!FIRST || i0 + k >= 4)  win_stats(s1_5,  s2_5,  0.2f,  0.25f,      mu, isd);
            else { mu = mu5i;  isd = isd5i; }
            fan += (v - mu) * isd * al0;
            if (!FIRST || i0 + k >= 9)  win_stats(s1_10, s2_10, 0.1f,  1.f / 9.f,  mu, isd);
            else { mu = mu10i; isd = isd10i; }
            fan += (v - mu) * isd * al1;
            if (!FIRST || i0 + k >= 19) win_stats(s1_20, s2_20, 0.05f, 1.f / 19.f, mu, isd);
            else { mu = mu20i; isd = isd20i; }
            fan += (v - mu) * isd * al2;

            if (PASS == 0) {
                ls1 += fan; ls2 += fan * fan;
            } else {
                outbh[t * H_DIM] = v + fmaf(fan, A, Bc);
            }
        }
    }
}

// PASS 0: FAN -> per-block per-h sum/sumsq partials (slice membership applied in reduce).
// PASS 1: recompute FAN identically, y = fan*A+B (A,B hoisted per block), residual, out.
// REGISTER NOTE: needs ~80 VGPRs live (hist[32] + sums). On this toolchain the
// 2nd __launch_bounds__ arg caps VGPR at ~512/(2w): (256,6)->40 VGPR, (256,4)->64,
// both spill hist to scratch (R3: 858 MB, R4: 306 MB scratch writes). Plain
// __launch_bounds__(256) -> ~72 VGPR, zero scratch (R2). DO NOT add a min-waves hint.
template <int PASS>
__global__ __launch_bounds__(256)
void fan_kernel(const float* __restrict__ x, const float* __restrict__ alpha,
                const float* __restrict__ gamma, const float* __restrict__ beta,
                float* __restrict__ part, const float* __restrict__ acc,
                float* __restrict__ out) {
    const int blk = blockIdx.x;
    const int b = blk / NCH;
    const int c = blk % NCH;
    const int h = threadIdx.x;
    const int t0 = c * CHUNK;
    const float* xbh = x + (size_t)b * T_DIM * H_DIM + h;
    float* outbh = out + (size_t)b * T_DIM * H_DIM + h;

    // softmax over alpha[h][0..2]
    const float a0 = alpha[h * 3 + 0], a1 = alpha[h * 3 + 1], a2 = alpha[h * 3 + 2];
    const float mx = fmaxf(a0, fmaxf(a1, a2));
    const float e0 = __expf(a0 - mx), e1 = __expf(a1 - mx), e2 = __expf(a2 - mx);
    const float einv = 1.0f / (e0 + e1 + e2);
    const float al0 = e0 * einv, al1 = e1 * einv, al2 = e2 * einv;

    // PASS1: fold SAN into y = fan*A + B. Regions are chunk-aligned:
    // slice0=[0,1536) (c<24), slice1=[1024,2048) (c>=16), overlap c in [16,24).
    float A = 0.f, Bc = 0.f;
    if (PASS == 1) {
        const float N0 = 64.0f * 1536.0f, N1 = 64.0f * 1024.0f;
        float S10 = acc[0 * H_DIM + h], S20 = acc[1 * H_DIM + h];
        float S11 = acc[2 * H_DIM + h], S21 = acc[3 * H_DIM + h];
        float mu0 = S10 / N0;
        float v0 = fmaxf((S20 - S10 * S10 / N0) / (N0 - 1.0f), 0.0f);
        float isd0 = 1.0f / fmaxf(sqrtf(v0), EPS_F);
        float mu1 = S11 / N1;
        float v1 = fmaxf((S21 - S11 * S11 / N1) / (N1 - 1.0f), 0.0f);
        float isd1 = 1.0f / fmaxf(sqrtf(v1), EPS_F);
        float A0 = isd0 * gamma[0 * H_DIM + h], B0 = beta[0 * H_DIM + h] - mu0 * A0;
        float A1 = isd1 * gamma[1 * H_DIM + h], B1 = beta[1 * H_DIM + h] - mu1 * A1;
        const float r1 = 1.0f / 1.0001f, r2 = 1.0f / 2.0001f;
        if (c < 16)      { A = A0 * r1;        Bc = B0 * r1; }
        else if (c >= 24){ A = A1 * r1;        Bc = B1 * r1; }
        else             { A = (A0 + A1) * r2; Bc = (B0 + B1) * r2; }
    }

    float ls1 = 0.0f, ls2 = 0.0f;

    if (c == 0) {
        // Edge stats: windows [0,w) used for t < w-1 (reference edge-pad semantics).
        float mu5i, isd5i, mu10i, isd10i, mu20i, isd20i;
        float c1 = 0.f, c2 = 0.f;
#pragma unroll
        for (int j = 0; j < 20; ++j) {
            float v = xbh[j * H_DIM];
            c1 += v; c2 += v * v;
            if (j == 4)  win_stats(c1, c2, 0.2f,  0.25f,      mu5i,  isd5i);
            if (j == 9)  win_stats(c1, c2, 0.1f,  1.f / 9.f,  mu10i, isd10i);
            if (j == 19) win_stats(c1, c2, 0.05f, 1.f / 19.f, mu20i, isd20i);
        }
        run_chunk<PASS, true>(xbh, t0, al0, al1, al2, A, Bc, outbh, ls1, ls2,
                              mu5i, isd5i, mu10i, isd10i, mu20i, isd20i);
    } else {
        run_chunk<PASS, false>(xbh, t0, al0, al1, al2, A, Bc, outbh, ls1, ls2,
                               0.f, 0.f, 0.f, 0.f, 0.f, 0.f);
    }

    if (PASS == 0) {
        part[(0 * NCB + blk) * H_DIM + h] = ls1;
        part[(1 * NCB + blk) * H_DIM + h] = ls2;
    }
}

// 32 blocks: (slice k, 1/16th of blocks). Membership by chunk index:
// slice0: c<24, slice1: c>=16. Atomic-add into acc[4][256].
__global__ __launch_bounds__(256)
void reduce_kernel(const float* __restrict__ part, float* __restrict__ acc) {
    const int h = threadIdx.x;
    const int k = blockIdx.x >> 4;     // slice 0/1
    const int g = blockIdx.x & 15;
    float a1 = 0.f, a2 = 0.f;
    for (int i = 0; i < NCB / 16; ++i) {
        const int blk = g * (NCB / 16) + i;
        const int c = blk % NCH;
        const bool member = (k == 0) ? (c < 24) : (c >= 16);
        if (member) {
            a1 += part[(0 * NCB + blk) * H_DIM + h];
            a2 += part[(1 * NCB + blk) * H_DIM + h];
        }
    }
    atomicAdd(&acc[(2 * k)     * H_DIM + h], a1);
    atomicAdd(&acc[(2 * k + 1) * H_DIM + h], a2);
}

extern "C" void kernel_launch(void* const* d_in, const int* in_sizes, int n_in,
                              void* d_out, int out_size, void* d_ws, size_t ws_size,
                              hipStream_t stream) {
    const float* x     = (const float*)d_in[0];
    const float* alpha = (const float*)d_in[1];
    const float* gamma = (const float*)d_in[2];
    const float* beta  = (const float*)d_in[3];
    float* out  = (float*)d_out;
    float* part = (float*)d_ws;                       // 2*NCB*H_DIM floats = 4 MB
    float* acc  = part + 2 * NCB * H_DIM;             // 4*H_DIM floats = 4 KB

    hipMemsetAsync(acc, 0, 4 * H_DIM * sizeof(float), stream);
    fan_kernel<0><<<NCB, H_DIM, 0, stream>>>(x, alpha, gamma, beta, part, acc, out);
    reduce_kernel<<<32, H_DIM, 0, stream>>>(part, acc);
    fan_kernel<1><<<NCB, H_DIM, 0, stream>>>(x, alpha, gamma, beta, part, acc, out);
}

// Round 6
// 356.993 us; speedup vs baseline: 2.0874x; 1.0234x over previous
//
#include <hip/hip_runtime.h>
#include <hip/hip_fp16.h>

#define T_DIM 2048
#define H_DIM 256
#define B_DIM 64
#define CHUNK 64
#define NCH (T_DIM / CHUNK)   /* 32 chunks per batch row */
#define NCB (B_DIM * NCH)     /* 2048 blocks */
#define EPS_F 1e-4f
#define R1 (1.0f / 1.0001f)
#define R2 (1.0f / 2.0001f)

// mu and inv-sd (= 1/max(sqrt(var),EPS)) from window sums.
__device__ __forceinline__ void win_stats(float s1, float s2, float inv_w, float inv_wm1,
                                          float& mu, float& isd) {
    mu = s1 * inv_w;
    float var = fmaxf((s2 - s1 * s1 * inv_w) * inv_wm1, 0.0f);
    // 1/max(sqrt(var),1e-4) == min(rsqrt(var), 1e4); rsqrt(0)=inf -> 1e4. Matches ref.
    isd = fminf(rsqrtf(var), 1e4f);
}

// FAN for one 64-t chunk of one (b, h) column. Stashes fan (MODE 0: fp16 to ws,
// MODE 1: fp32 to d_out) and accumulates sum/sumsq partials for SAN stats.
template <int MODE, bool FIRST>
__device__ __forceinline__ void run_chunk(
    const float* __restrict__ xbh, __half* __restrict__ s16bh, float* __restrict__ s32bh,
    int t0, float al0, float al1, float al2,
    float& ls1, float& ls2,
    float mu5i, float isd5i, float mu10i, float isd10i, float mu20i, float isd20i) {

    float s1_5 = 0.f, s2_5 = 0.f, s1_10 = 0.f, s2_10 = 0.f, s1_20 = 0.f, s2_20 = 0.f;
    float hist[32];

    if (FIRST) {
#pragma unroll
        for (int j = 0; j < 32; ++j) hist[j] = 0.0f;
    } else {
        // Warm-up: window sums covering [t0-20, t0); delay-line positions 12..31.
#pragma unroll
        for (int j = 1; j <= 20; ++j) {
            float v = xbh[(t0 - j) * H_DIM];
            hist[(32 - j) & 31] = v;
            s1_20 += v; s2_20 += v * v;
            if (j <= 10) { s1_10 += v; s2_10 += v * v; }
            if (j <= 5)  { s1_5  += v; s2_5  += v * v; }
        }
    }

    for (int i0 = 0; i0 < CHUNK; i0 += 32) {
#pragma unroll
        for (int k = 0; k < 32; ++k) {
            const int t = t0 + i0 + k;   // FIRST => t == i0+k (compile-time per k)
            const float v = xbh[t * H_DIM];
            hist[k] = v;
            s1_5  += v; s2_5  += v * v;
            s1_10 += v; s2_10 += v * v;
            s1_20 += v; s2_20 += v * v;
            if (!FIRST || i0 + k >= 5)  { float o = hist[(k - 5)  & 31]; s1_5  -= o; s2_5  -= o * o; }
            if (!FIRST || i0 + k >= 10) { float o = hist[(k - 10) & 31]; s1_10 -= o; s2_10 -= o * o; }
            if (!FIRST || i0 + k >= 20) { float o = hist[(k - 20) & 31]; s1_20 -= o; s2_20 -= o * o; }

            float mu, isd, fan = 0.0f;
            if (!FIRST || i0 + k >= 4)  win_stats(s1_5,  s2_5,  0.2f,  0.25f,      mu, isd);
            else { mu = mu5i;  isd = isd5i; }
            fan += (v - mu) * isd * al0;
            if (!FIRST || i0 + k >= 9)  win_stats(s1_10, s2_10, 0.1f,  1.f / 9.f,  mu, isd);
            else { mu = mu10i; isd = isd10i; }
            fan += (v - mu) * isd * al1;
            if (!FIRST || i0 + k >= 19) win_stats(s1_20, s2_20, 0.05f, 1.f / 19.f, mu, isd);
            else { mu = mu20i; isd = isd20i; }
            fan += (v - mu) * isd * al2;

            ls1 += fan; ls2 += fan * fan;
            if (MODE == 0) s16bh[t * H_DIM] = __float2half(fan);
            else           s32bh[t * H_DIM] = fan;
        }
    }
}

// REGISTER NOTE: needs ~88 VGPRs live (hist[32] + sums). On this toolchain the
// 2nd __launch_bounds__ arg caps VGPR at ~512/(2w): (256,6)->40 VGPR, (256,4)->64,
// both spill hist to scratch (R3: 858 MB, R4: 306 MB scratch writes). Plain
// __launch_bounds__(256) -> 88 VGPR, zero scratch. DO NOT add a min-waves hint.
template <int MODE>
__global__ __launch_bounds__(256)
void fan_kernel(const float* __restrict__ x, const float* __restrict__ alpha,
                float* __restrict__ part, __half* __restrict__ stash16,
                float* __restrict__ stash32) {
    const int blk = blockIdx.x;
    const int b = blk / NCH;
    const int c = blk % NCH;
    const int h = threadIdx.x;
    const int t0 = c * CHUNK;
    const size_t base = (size_t)b * T_DIM * H_DIM + h;
    const float* xbh = x + base;
    __half* s16bh = (MODE == 0) ? stash16 + base : nullptr;
    float*  s32bh = (MODE == 1) ? stash32 + base : nullptr;

    // softmax over alpha[h][0..2]
    const float a0 = alpha[h * 3 + 0], a1 = alpha[h * 3 + 1], a2 = alpha[h * 3 + 2];
    const float mx = fmaxf(a0, fmaxf(a1, a2));
    const float e0 = __expf(a0 - mx), e1 = __expf(a1 - mx), e2 = __expf(a2 - mx);
    const float einv = 1.0f / (e0 + e1 + e2);
    const float al0 = e0 * einv, al1 = e1 * einv, al2 = e2 * einv;

    float ls1 = 0.0f, ls2 = 0.0f;

    if (c == 0) {
        // Edge stats: windows [0,w) used for t < w-1 (reference edge-pad semantics).
        float mu5i, isd5i, mu10i, isd10i, mu20i, isd20i;
        float c1 = 0.f, c2 = 0.f;
#pragma unroll
        for (int j = 0; j < 20; ++j) {
            float v = xbh[j * H_DIM];
            c1 += v; c2 += v * v;
            if (j == 4)  win_stats(c1, c2, 0.2f,  0.25f,      mu5i,  isd5i);
            if (j == 9)  win_stats(c1, c2, 0.1f,  1.f / 9.f,  mu10i, isd10i);
            if (j == 19) win_stats(c1, c2, 0.05f, 1.f / 19.f, mu20i, isd20i);
        }
        run_chunk<MODE, true>(xbh, s16bh, s32bh, t0, al0, al1, al2, ls1, ls2,
                              mu5i, isd5i, mu10i, isd10i, mu20i, isd20i);
    } else {
        run_chunk<MODE, false>(xbh, s16bh, s32bh, t0, al0, al1, al2, ls1, ls2,
                               0.f, 0.f, 0.f, 0.f, 0.f, 0.f);
    }

    part[(0 * NCB + blk) * H_DIM + h] = ls1;
    part[(1 * NCB + blk) * H_DIM + h] = ls2;
}

// 32 blocks: (slice k, 1/16th of blocks). Membership by chunk index:
// slice0: c<24, slice1: c>=16. Atomic-add into acc[4][256].
__global__ __launch_bounds__(256)
void reduce_kernel(const float* __restrict__ part, float* __restrict__ acc) {
    const int h = threadIdx.x;
    const int k = blockIdx.x >> 4;     // slice 0/1
    const int g = blockIdx.x & 15;
    float a1 = 0.f, a2 = 0.f;
    for (int i = 0; i < NCB / 16; ++i) {
        const int blk = g * (NCB / 16) + i;
        const int c = blk % NCH;
        const bool member = (k == 0) ? (c < 24) : (c >= 16);
        if (member) {
            a1 += part[(0 * NCB + blk) * H_DIM + h];
            a2 += part[(1 * NCB + blk) * H_DIM + h];
        }
    }
    atomicAdd(&acc[(2 * k)     * H_DIM + h], a1);
    atomicAdd(&acc[(2 * k + 1) * H_DIM + h], a2);
}

// 1 block: acc -> per-h affine coefs A0,B0,A1,B1 (SAN z = fan*A + B per slice).
__global__ __launch_bounds__(256)
void finalize_kernel(const float* __restrict__ acc, const float* __restrict__ gamma,
                     const float* __restrict__ beta, float* __restrict__ coef) {
    const int h = threadIdx.x;
    const float N0 = 64.0f * 1536.0f, N1 = 64.0f * 1024.0f;
    float S10 = acc[0 * H_DIM + h], S20 = acc[1 * H_DIM + h];
    float S11 = acc[2 * H_DIM + h], S21 = acc[3 * H_DIM + h];
    float mu0 = S10 / N0;
    float v0 = fmaxf((S20 - S10 * S10 / N0) / (N0 - 1.0f), 0.0f);
    float isd0 = 1.0f / fmaxf(sqrtf(v0), EPS_F);
    float mu1 = S11 / N1;
    float v1 = fmaxf((S21 - S11 * S11 / N1) / (N1 - 1.0f), 0.0f);
    float isd1 = 1.0f / fmaxf(sqrtf(v1), EPS_F);
    float A0 = isd0 * gamma[0 * H_DIM + h];
    float A1 = isd1 * gamma[1 * H_DIM + h];
    coef[0 * H_DIM + h] = A0;
    coef[1 * H_DIM + h] = beta[0 * H_DIM + h] - mu0 * A0;
    coef[2 * H_DIM + h] = A1;
    coef[3 * H_DIM + h] = beta[1 * H_DIM + h] - mu1 * A1;
}

// Streaming epilogue: out = x + fan*A + B. Block = (b, 64-t chunk); wave w covers
// t in [t0+16w, t0+16w+16); lane covers h = 4*lane (float4/half2x2 accesses).
// Slice regions are 64-t aligned -> (A,B) select is block-uniform.
template <bool HALF>
__global__ __launch_bounds__(256)
void epilogue_kernel(const float* __restrict__ x, const void* __restrict__ fanp,
                     const float* __restrict__ coef, float* __restrict__ out) {
    const int blk = blockIdx.x;
    const int b = blk / NCH;
    const int c = blk % NCH;
    const int wave = threadIdx.x >> 6;
    const int lane = threadIdx.x & 63;
    const int h4 = lane * 4;

    float4 A0 = *(const float4*)&coef[0 * H_DIM + h4];
    float4 B0 = *(const float4*)&coef[1 * H_DIM + h4];
    float4 A1 = *(const float4*)&coef[2 * H_DIM + h4];
    float4 B1 = *(const float4*)&coef[3 * H_DIM + h4];
    float4 A, Bv;
    if (c < 16) {
        A  = make_float4(A0.x * R1, A0.y * R1, A0.z * R1, A0.w * R1);
        Bv = make_float4(B0.x * R1, B0.y * R1, B0.z * R1, B0.w * R1);
    } else if (c >= 24) {
        A  = make_float4(A1.x * R1, A1.y * R1, A1.z * R1, A1.w * R1);
        Bv = make_float4(B1.x * R1, B1.y * R1, B1.z * R1, B1.w * R1);
    } else {
        A  = make_float4((A0.x + A1.x) * R2, (A0.y + A1.y) * R2, (A0.z + A1.z) * R2, (A0.w + A1.w) * R2);
        Bv = make_float4((B0.x + B1.x) * R2, (B0.y + B1.y) * R2, (B0.z + B1.z) * R2, (B0.w + B1.w) * R2);
    }

    const int tbase = c * CHUNK + wave * 16;
#pragma unroll 4
    for (int i = 0; i < 16; ++i) {
        const size_t idx = ((size_t)b * T_DIM + tbase + i) * H_DIM + h4;
        float4 xv = *(const float4*)&x[idx];
        float4 fv;
        if (HALF) {
            const __half2* fp = (const __half2*)((const __half*)fanp + idx);
            float2 f0 = __half22float2(fp[0]);
            float2 f1 = __half22float2(fp[1]);
            fv = make_float4(f0.x, f0.y, f1.x, f1.y);
        } else {
            fv = *(const float4*)&((const float*)fanp)[idx];
        }
        float4 o;
        o.x = xv.x + fmaf(fv.x, A.x, Bv.x);
        o.y = xv.y + fmaf(fv.y, A.y, Bv.y);
        o.z = xv.z + fmaf(fv.z, A.z, Bv.z);
        o.w = xv.w + fmaf(fv.w, A.w, Bv.w);
        *(float4*)&out[idx] = o;
    }
}

extern "C" void kernel_launch(void* const* d_in, const int* in_sizes, int n_in,
                              void* d_out, int out_size, void* d_ws, size_t ws_size,
                              hipStream_t stream) {
    const float* x     = (const float*)d_in[0];
    const float* alpha = (const float*)d_in[1];
    const float* gamma = (const float*)d_in[2];
    const float* beta  = (const float*)d_in[3];
    float* out  = (float*)d_out;

    float* part = (float*)d_ws;                          // 2*NCB*H floats = 4 MB
    float* acc  = part + 2 * NCB * H_DIM;                // 4*H floats = 4 KB
    float* coef = acc + 4 * H_DIM;                       // 4*H floats = 4 KB
    __half* stash16 = (__half*)(coef + 4 * H_DIM);       // B*T*H halves = 67 MB
    const size_t need = (size_t)(2 * NCB * H_DIM + 8 * H_DIM) * 4
                      + (size_t)B_DIM * T_DIM * H_DIM * 2;
    const bool half_path = (ws_size >= need);            // constant per process -> graph-safe

    hipMemsetAsync(acc, 0, 4 * H_DIM * sizeof(float), stream);
    if (half_path) {
        fan_kernel<0><<<NCB, H_DIM, 0, stream>>>(x, alpha, part, stash16, nullptr);
    } else {
        // Fallback: stash fp32 fan in d_out; epilogue overwrites it in place.
        fan_kernel<1><<<NCB, H_DIM, 0, stream>>>(x, alpha, part, nullptr, out);
    }
    reduce_kernel<<<32, H_DIM, 0, stream>>>(part, acc);
    finalize_kernel<<<1, H_DIM, 0, stream>>>(acc, gamma, beta, coef);
    if (half_path) {
        epilogue_kernel<true><<<NCB, 256, 0, stream>>>(x, stash16, coef, out);
    } else {
        epilogue_kernel<false><<<NCB, 256, 0, stream>>>(x, out, coef, out);
    }
}